// Round 13
// baseline (177.769 us; speedup 1.0000x reference)
//
#include <hip/hip_runtime.h>
#include <math.h>

#define N_NODES 100000
#define N_EDGES 1600000
#define IN_DIM 128
#define HEADS 4
#define OUT_DIM 32
#define HD 128  // HEADS*OUT_DIM
#define NEG_SLOPE 0.2f

#define EBLK 2048       // edges per bucket-sort block
#define NBLK_E 782      // ceil(N_EDGES/EBLK)
#define NBIN 391        // ceil(N_NODES/256) coarse buckets (256 nodes each)
#define GH_TOT (NBIN * NBLK_E)  // 305762
#define S1_BLKS 150     // ceil(GH_TOT/2048)

typedef __attribute__((ext_vector_type(8))) short short8;
typedef __attribute__((ext_vector_type(4))) float f32x4;

__device__ inline ushort f2bf(float f) {
    // round-to-nearest-even fp32 -> bf16
    uint u = __float_as_uint(f);
    u += 0x7fffu + ((u >> 16) & 1u);
    return (ushort)(u >> 16);
}

// ---------------- K1: x_proj = x @ W^T  (bf16 MFMA; A staged in LDS, B from L1) ------
// A: coalesced float4 loads -> swizzled 16KB LDS tile (R11's proven staging).
// B: 16B/lane register loads from pre-converted wb (32KB, L1-resident; each fragment
//    read exactly once). Out-tile reuses the A buffer after the MFMA loop.
// LDS total 16KB (vs 48KB in R11) -> ~2.7x the occupancy with identical coalescing.
__global__ __launch_bounds__(256) void k_gemm(const float* __restrict__ x,
                                              const ushort* __restrict__ wb,
                                              ushort* __restrict__ xp,
                                              const float* __restrict__ att_src,
                                              const float* __restrict__ att_dst,
                                              float* __restrict__ asrc,
                                              float* __restrict__ adst) {
    __shared__ ushort lA[64 * 128];  // 16 KB: A-tile, then reused as out-tile
    const int tid = threadIdx.x;
    const long row_base = (long)blockIdx.x * 64;

    // ---- stage A (x rows, fp32 -> bf16, swizzled, coalesced) ----
    {
        const int r = tid >> 2;
        const int c0 = (tid & 3) * 32;
        const long row = row_base + r;
        const float* src = x + row * IN_DIM + c0;
#pragma unroll
        for (int i = 0; i < 4; i++) {  // 8 cols per iter
            float4 va, vb;
            if (row < N_NODES) {
                va = *(const float4*)(src + 8 * i);
                vb = *(const float4*)(src + 8 * i + 4);
            } else {
                va = make_float4(0.f, 0.f, 0.f, 0.f);
                vb = va;
            }
            ushort h[8] = {f2bf(va.x), f2bf(va.y), f2bf(va.z), f2bf(va.w),
                           f2bf(vb.x), f2bf(vb.y), f2bf(vb.z), f2bf(vb.w)};
            uint byte = (uint)(r * 256 + (c0 + 8 * i) * 2);
            byte ^= (uint)((r & 7) << 4);
            *(uint4*)((char*)lA + byte) = *(const uint4*)h;
        }
    }
    __syncthreads();

    // ---- MFMA main: wave w owns rows w*16..w*16+15, all 128 cols ----
    const int w = tid >> 6;
    const int lane = tid & 63;
    const int l15 = lane & 15;
    const int g8 = (lane >> 4) * 8;  // k sub-offset (consistent convention for A and B)
    const int arow = w * 16 + l15;
    const short8* wv = (const short8*)wb;  // W[c][k] bf16, row = 16 chunks of 8

    f32x4 acc[8];
#pragma unroll
    for (int nt = 0; nt < 8; nt++) acc[nt] = (f32x4){0.f, 0.f, 0.f, 0.f};

#pragma unroll
    for (int t = 0; t < 4; t++) {
        uint ab = (uint)(arow * 256 + (t * 32 + g8) * 2);
        ab ^= (uint)((arow & 7) << 4);
        short8 af = *(const short8*)((const char*)lA + ab);
#pragma unroll
        for (int nt = 0; nt < 8; nt++) {
            short8 bfr = wv[(nt * 16 + l15) * 16 + t * 4 + (g8 >> 3)];
            acc[nt] = __builtin_amdgcn_mfma_f32_16x16x32_bf16(af, bfr, acc[nt], 0, 0, 0);
        }
    }
    __syncthreads();  // done reading lA; reuse as out-tile

    // ---- write acc -> lA (linear [64][128] bf16 out-tile) ----
    // C/D layout: col = lane&15, row = 4*(lane>>4)+reg  [m89/m91]
    {
        const int m4 = 4 * (lane >> 4);
#pragma unroll
        for (int nt = 0; nt < 8; nt++) {
            int c = nt * 16 + l15;
#pragma unroll
            for (int r = 0; r < 4; r++) {
                lA[(w * 16 + m4 + r) * 128 + c] = f2bf(acc[nt][r]);
            }
        }
    }
    __syncthreads();

    // ---- epilogue: coalesced xp store + fused attention dots ----
    {
        const int r = tid >> 2;
        const long node = row_base + r;
        if (node < N_NODES) {
            const int h = tid & 3;
            const int c0 = h * 32;
            const uint4* s = (const uint4*)(lA + r * 128 + c0);
            uint4 v0 = s[0], v1 = s[1], v2 = s[2], v3 = s[3];
            uint4* d = (uint4*)(xp + node * HD + c0);
            d[0] = v0; d[1] = v1; d[2] = v2; d[3] = v3;
            const float* as = att_src + c0;
            const float* ad = att_dst + c0;
            float s0 = 0.f, s1 = 0.f;
            uint4 vv[4] = {v0, v1, v2, v3};
#pragma unroll
            for (int q = 0; q < 4; q++) {
                const uint* u = (const uint*)&vv[q];
#pragma unroll
                for (int p = 0; p < 4; p++) {
                    float f0 = __uint_as_float((u[p] & 0xffffu) << 16);
                    float f1 = __uint_as_float(u[p] & 0xffff0000u);
                    int cc = q * 8 + p * 2;
                    s0 = fmaf(f0, as[cc], s0);
                    s0 = fmaf(f1, as[cc + 1], s0);
                    s1 = fmaf(f0, ad[cc], s1);
                    s1 = fmaf(f1, ad[cc + 1], s1);
                }
            }
            asrc[node * HEADS + h] = s0;
            adst[node * HEADS + h] = s1;
        }
    }
}

// ---------------- P1: coarse histogram (LDS atomics only) + W bf16 pre-convert ------
__global__ __launch_bounds__(256) void k_chist(const int* __restrict__ ei,
                                               int* __restrict__ ghist,
                                               const float* __restrict__ W,
                                               ushort* __restrict__ wb) {
    __shared__ int h[NBIN];
    const int tid = threadIdx.x;
    if (blockIdx.x < 16) {
        int i = (blockIdx.x * 256 + tid) * 4;
        float4 v = *(const float4*)(W + i);
        ushort o[4] = {f2bf(v.x), f2bf(v.y), f2bf(v.z), f2bf(v.w)};
        *(ulong1*)(wb + i) = *(const ulong1*)o;
    }
    for (int i = tid; i < NBIN; i += 256) h[i] = 0;
    __syncthreads();
    const int base = blockIdx.x * EBLK;
#pragma unroll
    for (int i = 0; i < 8; i++) {
        int e = base + tid + i * 256;
        if (e < N_EDGES) atomicAdd(&h[ei[N_EDGES + e] >> 8], 1);
    }
    __syncthreads();
    for (int i = tid; i < NBIN; i += 256) ghist[i * NBLK_E + blockIdx.x] = h[i];
}

// ---------------- S1: per-block exclusive scan of ghist (2048/block) ----------------
__global__ __launch_bounds__(256) void k_s1(int* __restrict__ g, int* __restrict__ part) {
    __shared__ int lds[256];
    const int tid = threadIdx.x;
    const int base = blockIdx.x * 2048 + tid * 8;
    int v[8];
    int s = 0;
#pragma unroll
    for (int i = 0; i < 8; i++) {
        v[i] = (base + i < GH_TOT) ? g[base + i] : 0;
        s += v[i];
    }
    lds[tid] = s;
    __syncthreads();
    for (int o = 1; o < 256; o <<= 1) {
        int u = (tid >= o) ? lds[tid - o] : 0;
        __syncthreads();
        lds[tid] += u;
        __syncthreads();
    }
    int run = (tid == 0) ? 0 : lds[tid - 1];
#pragma unroll
    for (int i = 0; i < 8; i++) {
        int t = v[i];
        if (base + i < GH_TOT) g[base + i] = run;
        run += t;
    }
    if (tid == 255) part[blockIdx.x] = lds[255];
}

// ---------------- S23: apply partial prefixes (each block reduces its own prefix) ----
__global__ __launch_bounds__(256) void k_s23(int* __restrict__ g, const int* __restrict__ part) {
    __shared__ int red[256];
    const int tid = threadIdx.x;
    red[tid] = (tid < (int)blockIdx.x && tid < S1_BLKS) ? part[tid] : 0;
    __syncthreads();
    for (int o = 128; o > 0; o >>= 1) {
        if (tid < o) red[tid] += red[tid + o];
        __syncthreads();
    }
    const int p = red[0];
    const int base = blockIdx.x * 2048;
#pragma unroll
    for (int i = 0; i < 8; i++) {
        int idx = base + tid + i * 256;
        if (idx < GH_TOT) g[idx] += p;
    }
}

// ---------------- P3: scatter edges into coarse buckets (LDS atomics only) ----------
__global__ __launch_bounds__(256) void k_cscatter(const int* __restrict__ ei,
                                                  const int* __restrict__ ghist,
                                                  int* __restrict__ bpack) {
    __shared__ int base[NBIN];
    const int tid = threadIdx.x;
    for (int i = tid; i < NBIN; i += 256) base[i] = ghist[i * NBLK_E + blockIdx.x];
    __syncthreads();
    const int eb = blockIdx.x * EBLK;
#pragma unroll
    for (int i = 0; i < 8; i++) {
        int e = eb + tid + i * 256;
        if (e < N_EDGES) {
            int d = ei[N_EDGES + e];
            int s = ei[e];
            int p = atomicAdd(&base[d >> 8], 1);
            bpack[p] = (s << 8) | (d & 255);
        }
    }
}

// ---------------- P4: per-bucket fine CSR build (LDS atomics only) ----------------
__global__ __launch_bounds__(256) void k_fine(const int* __restrict__ ghist,
                                              const int* __restrict__ bpack,
                                              int* __restrict__ esrc,
                                              int* __restrict__ row_start) {
    __shared__ int cnt[256];
    __shared__ int scn[256];
    __shared__ int off[256];
    const int tid = threadIdx.x;
    const int b = blockIdx.x;
    const int S = ghist[b * NBLK_E];
    const int E = (b == NBIN - 1) ? N_EDGES : ghist[(b + 1) * NBLK_E];
    const int m = E - S;
    cnt[tid] = 0;
    __syncthreads();
    for (int i = tid; i < m; i += 256) atomicAdd(&cnt[bpack[S + i] & 255], 1);
    __syncthreads();
    scn[tid] = cnt[tid];
    __syncthreads();
    for (int o = 1; o < 256; o <<= 1) {
        int u = (tid >= o) ? scn[tid - o] : 0;
        __syncthreads();
        scn[tid] += u;
        __syncthreads();
    }
    const int excl = (tid == 0) ? 0 : scn[tid - 1];
    off[tid] = excl;
    const int node = b * 256 + tid;
    if (node <= N_NODES) row_start[node] = S + excl;  // node==N_NODES lands here (b=390,tid=160)
    __syncthreads();
    for (int i = tid; i < m; i += 256) {
        int pk = bpack[S + i];
        int p = atomicAdd(&off[pk & 255], 1);
        esrc[S + p] = pk & ~255;  // src<<8 = pre-shifted xp byte offset
    }
}

// ---------------- K5: single-pass softmax + aggregation (1 wave/node) ----------------
__global__ __launch_bounds__(256) void k_aggregate(const int* __restrict__ row_start,
                                                   const int* __restrict__ esrc,
                                                   const char* __restrict__ asrcB,
                                                   const float4* __restrict__ adst4,
                                                   const char* __restrict__ xpB,
                                                   const float* __restrict__ bias,
                                                   float* __restrict__ out) {
    __shared__ float lw[4][64][4];  // [wave][edge][head] weights
    __shared__ int loff[4][64];     // [wave][edge] xp byte offsets
    const int wid = threadIdx.x >> 6;
    const int lane = threadIdx.x & 63;
    const int n = blockIdx.x * 4 + wid;
    if (n >= N_NODES) return;
    const int s0 = row_start[n];
    const int s1 = row_start[n + 1];
    const int h = lane >> 4;
    const uint lane4 = (uint)lane * 4;
    const float4 ad = adst4[n];  // wave-uniform

    float acc0 = 0.f, acc1 = 0.f, den = 0.f;

    for (int base = s0; base < s1; base += 64) {
        const int rem = s1 - base;
        const int cnt = rem < 64 ? rem : 64;
        const bool v = lane < cnt;
        int moff = v ? esrc[base + lane] : 0;  // src*256 (byte offset)
        float4 as = *(const float4*)(asrcB + (moff >> 4));  // src*16
        float tx = as.x + ad.x, ty = as.y + ad.y, tz = as.z + ad.z, tw = as.w + ad.w;
        tx = (tx >= 0.f) ? tx : NEG_SLOPE * tx;
        ty = (ty >= 0.f) ? ty : NEG_SLOPE * ty;
        tz = (tz >= 0.f) ? tz : NEG_SLOPE * tz;
        tw = (tw >= 0.f) ? tw : NEG_SLOPE * tw;
        float4 wv;
        wv.x = v ? __expf(fminf(tx, 80.f)) : 0.f;
        wv.y = v ? __expf(fminf(ty, 80.f)) : 0.f;
        wv.z = v ? __expf(fminf(tz, 80.f)) : 0.f;
        wv.w = v ? __expf(fminf(tw, 80.f)) : 0.f;
        loff[wid][lane] = moff;
        *(float4*)&lw[wid][lane][0] = wv;
        // same-wave LDS staging: compiler inserts lgkmcnt ordering

        const int cnt8v = (cnt + 7) & ~7;  // padded: dummy edges have weight 0
        for (int j = 0; j < cnt8v; j += 8) {
            float e0 = lw[wid][j + 0][h], e1 = lw[wid][j + 1][h];
            float e2 = lw[wid][j + 2][h], e3 = lw[wid][j + 3][h];
            float e4 = lw[wid][j + 4][h], e5 = lw[wid][j + 5][h];
            float e6 = lw[wid][j + 6][h], e7 = lw[wid][j + 7][h];
            int4 sv0 = *(const int4*)&loff[wid][j];      // uniform broadcast
            int4 sv1 = *(const int4*)&loff[wid][j + 4];
            uint g0 = *(const uint*)(xpB + ((uint)sv0.x + lane4));
            uint g1 = *(const uint*)(xpB + ((uint)sv0.y + lane4));
            uint g2 = *(const uint*)(xpB + ((uint)sv0.z + lane4));
            uint g3 = *(const uint*)(xpB + ((uint)sv0.w + lane4));
            uint g4 = *(const uint*)(xpB + ((uint)sv1.x + lane4));
            uint g5 = *(const uint*)(xpB + ((uint)sv1.y + lane4));
            uint g6 = *(const uint*)(xpB + ((uint)sv1.z + lane4));
            uint g7 = *(const uint*)(xpB + ((uint)sv1.w + lane4));
            den += ((e0 + e1) + (e2 + e3)) + ((e4 + e5) + (e6 + e7));
            acc0 = fmaf(e0, __uint_as_float(g0 << 16), acc0);
            acc1 = fmaf(e0, __uint_as_float(g0 & 0xffff0000u), acc1);
            acc0 = fmaf(e1, __uint_as_float(g1 << 16), acc0);
            acc1 = fmaf(e1, __uint_as_float(g1 & 0xffff0000u), acc1);
            acc0 = fmaf(e2, __uint_as_float(g2 << 16), acc0);
            acc1 = fmaf(e2, __uint_as_float(g2 & 0xffff0000u), acc1);
            acc0 = fmaf(e3, __uint_as_float(g3 << 16), acc0);
            acc1 = fmaf(e3, __uint_as_float(g3 & 0xffff0000u), acc1);
            acc0 = fmaf(e4, __uint_as_float(g4 << 16), acc0);
            acc1 = fmaf(e4, __uint_as_float(g4 & 0xffff0000u), acc1);
            acc0 = fmaf(e5, __uint_as_float(g5 << 16), acc0);
            acc1 = fmaf(e5, __uint_as_float(g5 & 0xffff0000u), acc1);
            acc0 = fmaf(e6, __uint_as_float(g6 << 16), acc0);
            acc1 = fmaf(e6, __uint_as_float(g6 & 0xffff0000u), acc1);
            acc0 = fmaf(e7, __uint_as_float(g7 << 16), acc0);
            acc1 = fmaf(e7, __uint_as_float(g7 & 0xffff0000u), acc1);
        }
    }
    float inv = 1.f / (den + 1e-12f);
    float2 b2 = ((const float2*)bias)[lane];
    float2 o;
    o.x = acc0 * inv + b2.x;
    o.y = acc1 * inv + b2.y;
    ((float2*)(out + (long)n * HD))[lane] = o;
}

extern "C" void kernel_launch(void* const* d_in, const int* in_sizes, int n_in,
                              void* d_out, int out_size, void* d_ws, size_t ws_size,
                              hipStream_t stream) {
    const float* x = (const float*)d_in[0];
    const int* ei = (const int*)d_in[1];
    const float* W = (const float*)d_in[2];
    const float* att_src = (const float*)d_in[3];
    const float* att_dst = (const float*)d_in[4];
    const float* bias = (const float*)d_in[5];
    float* out = (float*)d_out;
    char* ws = (char*)d_ws;

    // workspace layout (bytes), 16B-aligned
    ushort* xp       = (ushort*)(ws + 0);         // 25,600,000 (bf16 x_proj)
    float* asrc      = (float*)(ws + 25600000);   //  1,600,000
    float* adst      = (float*)(ws + 27200000);   //  1,600,000
    int* esrc        = (int*)(ws + 28800000);     //  6,400,000
    int* bpack       = (int*)(ws + 35200000);     //  6,400,000
    int* ghist       = (int*)(ws + 41600000);     //  1,223,048 (391*782 ints)
    int* part        = (int*)(ws + 42823648);     //        600
    int* row_start   = (int*)(ws + 42824256);     //    400,004
    ushort* wb       = (ushort*)(ws + 43224272);  //     32,768 (bf16 W)
    // total ~43.3 MB; no zero-init needed (every buffer fully written before read)

    k_chist<<<NBLK_E, 256, 0, stream>>>(ei, ghist, W, wb);
    k_s1<<<S1_BLKS, 256, 0, stream>>>(ghist, part);
    k_s23<<<S1_BLKS, 256, 0, stream>>>(ghist, part);
    k_cscatter<<<NBLK_E, 256, 0, stream>>>(ei, ghist, bpack);
    k_gemm<<<(N_NODES + 63) / 64, 256, 0, stream>>>(x, wb, xp, att_src, att_dst, asrc, adst);
    k_fine<<<NBIN, 256, 0, stream>>>(ghist, bpack, esrc, row_start);
    k_aggregate<<<(N_NODES + 3) / 4, 256, 0, stream>>>(row_start, esrc,
                                                       (const char*)asrc, (const float4*)adst,
                                                       (const char*)xp, bias, out);
}

// Round 14
// 160.227 us; speedup vs baseline: 1.1095x; 1.1095x over previous
//
#include <hip/hip_runtime.h>
#include <math.h>

#define N_NODES 100000
#define N_EDGES 1600000
#define IN_DIM 128
#define HEADS 4
#define OUT_DIM 32
#define HD 128  // HEADS*OUT_DIM
#define NEG_SLOPE 0.2f

#define EBLK 2048       // edges per bucket-sort block
#define NBLK_E 782      // ceil(N_EDGES/EBLK)
#define NBIN 391        // ceil(N_NODES/256) coarse buckets (256 nodes each)
#define GH_TOT (NBIN * NBLK_E)  // 305762
#define S1_BLKS 150     // ceil(GH_TOT/2048)

typedef __attribute__((ext_vector_type(8))) short short8;
typedef __attribute__((ext_vector_type(4))) float f32x4;

__device__ inline ushort f2bf(float f) {
    // round-to-nearest-even fp32 -> bf16
    uint u = __float_as_uint(f);
    u += 0x7fffu + ((u >> 16) & 1u);
    return (ushort)(u >> 16);
}

// ---------------- K1: x_proj = x @ W^T  (bf16 MFMA, fused att-dots) ----------------
// R11 structure (best measured): A and B staged in swizzled LDS with coalesced loads,
// 4 waves x 8 N-tiles, out-tile bounce through lA. Only change vs R11: B stages from
// pre-converted bf16 wb (half the bytes, no f2bf in the B path).
__global__ __launch_bounds__(256) void k_gemm(const float* __restrict__ x,
                                              const ushort* __restrict__ wb,
                                              ushort* __restrict__ xp,
                                              const float* __restrict__ att_src,
                                              const float* __restrict__ att_dst,
                                              float* __restrict__ asrc,
                                              float* __restrict__ adst) {
    __shared__ ushort lA[64 * 128];   // 16 KB
    __shared__ ushort lB[128 * 128];  // 32 KB
    const int tid = threadIdx.x;
    const long row_base = (long)blockIdx.x * 64;

    // ---- stage A (x rows, fp32 -> bf16, swizzled) ----
    {
        const int r = tid >> 2;
        const int c0 = (tid & 3) * 32;
        const long row = row_base + r;
        const float* src = x + row * IN_DIM + c0;
#pragma unroll
        for (int i = 0; i < 4; i++) {  // 8 cols per iter
            float4 va, vb;
            if (row < N_NODES) {
                va = *(const float4*)(src + 8 * i);
                vb = *(const float4*)(src + 8 * i + 4);
            } else {
                va = make_float4(0.f, 0.f, 0.f, 0.f);
                vb = va;
            }
            ushort h[8] = {f2bf(va.x), f2bf(va.y), f2bf(va.z), f2bf(va.w),
                           f2bf(vb.x), f2bf(vb.y), f2bf(vb.z), f2bf(vb.w)};
            uint byte = (uint)(r * 256 + (c0 + 8 * i) * 2);
            byte ^= (uint)((r & 7) << 4);
            *(uint4*)((char*)lA + byte) = *(const uint4*)h;
        }
    }
    // ---- stage B (wb bf16 rows, swizzled copy): lB[c][k] = wb[c][k] ----
    {
        const int c = tid >> 1;
        const int k0 = (tid & 1) * 64;
        const ushort* src = wb + c * IN_DIM + k0;
#pragma unroll
        for (int i = 0; i < 8; i++) {  // 8 bf16 per iter (16 B)
            uint4 v = *(const uint4*)(src + 8 * i);
            uint byte = (uint)(c * 256 + (k0 + 8 * i) * 2);
            byte ^= (uint)((c & 7) << 4);
            *(uint4*)((char*)lB + byte) = v;
        }
    }
    __syncthreads();

    // ---- MFMA main: wave w owns rows w*16..w*16+15, all 128 cols ----
    const int w = tid >> 6;
    const int lane = tid & 63;
    const int l15 = lane & 15;
    const int g8 = (lane >> 4) * 8;  // k sub-offset (consistent convention for A and B)
    const int arow = w * 16 + l15;

    f32x4 acc[8];
#pragma unroll
    for (int nt = 0; nt < 8; nt++) acc[nt] = (f32x4){0.f, 0.f, 0.f, 0.f};

#pragma unroll
    for (int t = 0; t < 4; t++) {
        uint ab = (uint)(arow * 256 + (t * 32 + g8) * 2);
        ab ^= (uint)((arow & 7) << 4);
        short8 af = *(const short8*)((const char*)lA + ab);
#pragma unroll
        for (int nt = 0; nt < 8; nt++) {
            int c = nt * 16 + l15;
            uint bb = (uint)(c * 256 + (t * 32 + g8) * 2);
            bb ^= (uint)((c & 7) << 4);
            short8 bfr = *(const short8*)((const char*)lB + bb);
            acc[nt] = __builtin_amdgcn_mfma_f32_16x16x32_bf16(af, bfr, acc[nt], 0, 0, 0);
        }
    }
    __syncthreads();  // done reading lA/lB; reuse lA as out-tile

    // ---- write acc -> lA (linear [64][128] bf16 out-tile) ----
    // C/D layout: col = lane&15, row = 4*(lane>>4)+reg  [m89/m91]
    {
        const int m4 = 4 * (lane >> 4);
#pragma unroll
        for (int nt = 0; nt < 8; nt++) {
            int c = nt * 16 + l15;
#pragma unroll
            for (int r = 0; r < 4; r++) {
                lA[(w * 16 + m4 + r) * 128 + c] = f2bf(acc[nt][r]);
            }
        }
    }
    __syncthreads();

    // ---- epilogue: coalesced xp store + fused attention dots ----
    {
        const int r = tid >> 2;
        const long node = row_base + r;
        if (node < N_NODES) {
            const int h = tid & 3;
            const int c0 = h * 32;
            const uint4* s = (const uint4*)(lA + r * 128 + c0);
            uint4 v0 = s[0], v1 = s[1], v2 = s[2], v3 = s[3];
            uint4* d = (uint4*)(xp + node * HD + c0);
            d[0] = v0; d[1] = v1; d[2] = v2; d[3] = v3;
            const float* as = att_src + c0;
            const float* ad = att_dst + c0;
            float s0 = 0.f, s1 = 0.f;
            uint4 vv[4] = {v0, v1, v2, v3};
#pragma unroll
            for (int q = 0; q < 4; q++) {
                const uint* u = (const uint*)&vv[q];
#pragma unroll
                for (int p = 0; p < 4; p++) {
                    float f0 = __uint_as_float((u[p] & 0xffffu) << 16);
                    float f1 = __uint_as_float(u[p] & 0xffff0000u);
                    int cc = q * 8 + p * 2;
                    s0 = fmaf(f0, as[cc], s0);
                    s0 = fmaf(f1, as[cc + 1], s0);
                    s1 = fmaf(f0, ad[cc], s1);
                    s1 = fmaf(f1, ad[cc + 1], s1);
                }
            }
            asrc[node * HEADS + h] = s0;
            adst[node * HEADS + h] = s1;
        }
    }
}

// ---------------- P1: coarse histogram (LDS atomics only) + W bf16 pre-convert ------
__global__ __launch_bounds__(256) void k_chist(const int* __restrict__ ei,
                                               int* __restrict__ ghist,
                                               const float* __restrict__ W,
                                               ushort* __restrict__ wb) {
    __shared__ int h[NBIN];
    const int tid = threadIdx.x;
    if (blockIdx.x < 16) {
        int i = (blockIdx.x * 256 + tid) * 4;
        float4 v = *(const float4*)(W + i);
        ushort o[4] = {f2bf(v.x), f2bf(v.y), f2bf(v.z), f2bf(v.w)};
        *(ulong1*)(wb + i) = *(const ulong1*)o;
    }
    for (int i = tid; i < NBIN; i += 256) h[i] = 0;
    __syncthreads();
    const int base = blockIdx.x * EBLK;
#pragma unroll
    for (int i = 0; i < 8; i++) {
        int e = base + tid + i * 256;
        if (e < N_EDGES) atomicAdd(&h[ei[N_EDGES + e] >> 8], 1);
    }
    __syncthreads();
    for (int i = tid; i < NBIN; i += 256) ghist[i * NBLK_E + blockIdx.x] = h[i];
}

// ---------------- S1: per-block exclusive scan of ghist (2048/block) ----------------
__global__ __launch_bounds__(256) void k_s1(int* __restrict__ g, int* __restrict__ part) {
    __shared__ int lds[256];
    const int tid = threadIdx.x;
    const int base = blockIdx.x * 2048 + tid * 8;
    int v[8];
    int s = 0;
#pragma unroll
    for (int i = 0; i < 8; i++) {
        v[i] = (base + i < GH_TOT) ? g[base + i] : 0;
        s += v[i];
    }
    lds[tid] = s;
    __syncthreads();
    for (int o = 1; o < 256; o <<= 1) {
        int u = (tid >= o) ? lds[tid - o] : 0;
        __syncthreads();
        lds[tid] += u;
        __syncthreads();
    }
    int run = (tid == 0) ? 0 : lds[tid - 1];
#pragma unroll
    for (int i = 0; i < 8; i++) {
        int t = v[i];
        if (base + i < GH_TOT) g[base + i] = run;
        run += t;
    }
    if (tid == 255) part[blockIdx.x] = lds[255];
}

// ---------------- S23: apply partial prefixes (each block reduces its own prefix) ----
__global__ __launch_bounds__(256) void k_s23(int* __restrict__ g, const int* __restrict__ part) {
    __shared__ int red[256];
    const int tid = threadIdx.x;
    red[tid] = (tid < (int)blockIdx.x && tid < S1_BLKS) ? part[tid] : 0;
    __syncthreads();
    for (int o = 128; o > 0; o >>= 1) {
        if (tid < o) red[tid] += red[tid + o];
        __syncthreads();
    }
    const int p = red[0];
    const int base = blockIdx.x * 2048;
#pragma unroll
    for (int i = 0; i < 8; i++) {
        int idx = base + tid + i * 256;
        if (idx < GH_TOT) g[idx] += p;
    }
}

// ---------------- P3: scatter edges into coarse buckets (LDS atomics only) ----------
__global__ __launch_bounds__(256) void k_cscatter(const int* __restrict__ ei,
                                                  const int* __restrict__ ghist,
                                                  int* __restrict__ bpack) {
    __shared__ int base[NBIN];
    const int tid = threadIdx.x;
    for (int i = tid; i < NBIN; i += 256) base[i] = ghist[i * NBLK_E + blockIdx.x];
    __syncthreads();
    const int eb = blockIdx.x * EBLK;
#pragma unroll
    for (int i = 0; i < 8; i++) {
        int e = eb + tid + i * 256;
        if (e < N_EDGES) {
            int d = ei[N_EDGES + e];
            int s = ei[e];
            int p = atomicAdd(&base[d >> 8], 1);
            bpack[p] = (s << 8) | (d & 255);
        }
    }
}

// ---------------- P4: per-bucket fine CSR build (LDS atomics only) ----------------
__global__ __launch_bounds__(256) void k_fine(const int* __restrict__ ghist,
                                              const int* __restrict__ bpack,
                                              int* __restrict__ esrc,
                                              int* __restrict__ row_start) {
    __shared__ int cnt[256];
    __shared__ int scn[256];
    __shared__ int off[256];
    const int tid = threadIdx.x;
    const int b = blockIdx.x;
    const int S = ghist[b * NBLK_E];
    const int E = (b == NBIN - 1) ? N_EDGES : ghist[(b + 1) * NBLK_E];
    const int m = E - S;
    cnt[tid] = 0;
    __syncthreads();
    for (int i = tid; i < m; i += 256) atomicAdd(&cnt[bpack[S + i] & 255], 1);
    __syncthreads();
    scn[tid] = cnt[tid];
    __syncthreads();
    for (int o = 1; o < 256; o <<= 1) {
        int u = (tid >= o) ? scn[tid - o] : 0;
        __syncthreads();
        scn[tid] += u;
        __syncthreads();
    }
    const int excl = (tid == 0) ? 0 : scn[tid - 1];
    off[tid] = excl;
    const int node = b * 256 + tid;
    if (node <= N_NODES) row_start[node] = S + excl;  // node==N_NODES lands here (b=390,tid=160)
    __syncthreads();
    for (int i = tid; i < m; i += 256) {
        int pk = bpack[S + i];
        int p = atomicAdd(&off[pk & 255], 1);
        esrc[S + p] = pk & ~255;  // src<<8 = pre-shifted xp byte offset
    }
}

// ---------------- K5: single-pass softmax + aggregation (1 wave/node) ----------------
__global__ __launch_bounds__(256) void k_aggregate(const int* __restrict__ row_start,
                                                   const int* __restrict__ esrc,
                                                   const char* __restrict__ asrcB,
                                                   const float4* __restrict__ adst4,
                                                   const char* __restrict__ xpB,
                                                   const float* __restrict__ bias,
                                                   float* __restrict__ out) {
    __shared__ float lw[4][64][4];  // [wave][edge][head] weights
    __shared__ int loff[4][64];     // [wave][edge] xp byte offsets
    const int wid = threadIdx.x >> 6;
    const int lane = threadIdx.x & 63;
    const int n = blockIdx.x * 4 + wid;
    if (n >= N_NODES) return;
    const int s0 = row_start[n];
    const int s1 = row_start[n + 1];
    const int h = lane >> 4;
    const uint lane4 = (uint)lane * 4;
    const float4 ad = adst4[n];  // wave-uniform

    float acc0 = 0.f, acc1 = 0.f, den = 0.f;

    for (int base = s0; base < s1; base += 64) {
        const int rem = s1 - base;
        const int cnt = rem < 64 ? rem : 64;
        const bool v = lane < cnt;
        int moff = v ? esrc[base + lane] : 0;  // src*256 (byte offset)
        float4 as = *(const float4*)(asrcB + (moff >> 4));  // src*16
        float tx = as.x + ad.x, ty = as.y + ad.y, tz = as.z + ad.z, tw = as.w + ad.w;
        tx = (tx >= 0.f) ? tx : NEG_SLOPE * tx;
        ty = (ty >= 0.f) ? ty : NEG_SLOPE * ty;
        tz = (tz >= 0.f) ? tz : NEG_SLOPE * tz;
        tw = (tw >= 0.f) ? tw : NEG_SLOPE * tw;
        float4 wv;
        wv.x = v ? __expf(fminf(tx, 80.f)) : 0.f;
        wv.y = v ? __expf(fminf(ty, 80.f)) : 0.f;
        wv.z = v ? __expf(fminf(tz, 80.f)) : 0.f;
        wv.w = v ? __expf(fminf(tw, 80.f)) : 0.f;
        loff[wid][lane] = moff;
        *(float4*)&lw[wid][lane][0] = wv;
        // same-wave LDS staging: compiler inserts lgkmcnt ordering

        const int cnt8v = (cnt + 7) & ~7;  // padded: dummy edges have weight 0
        for (int j = 0; j < cnt8v; j += 8) {
            float e0 = lw[wid][j + 0][h], e1 = lw[wid][j + 1][h];
            float e2 = lw[wid][j + 2][h], e3 = lw[wid][j + 3][h];
            float e4 = lw[wid][j + 4][h], e5 = lw[wid][j + 5][h];
            float e6 = lw[wid][j + 6][h], e7 = lw[wid][j + 7][h];
            int4 sv0 = *(const int4*)&loff[wid][j];      // uniform broadcast
            int4 sv1 = *(const int4*)&loff[wid][j + 4];
            uint g0 = *(const uint*)(xpB + ((uint)sv0.x + lane4));
            uint g1 = *(const uint*)(xpB + ((uint)sv0.y + lane4));
            uint g2 = *(const uint*)(xpB + ((uint)sv0.z + lane4));
            uint g3 = *(const uint*)(xpB + ((uint)sv0.w + lane4));
            uint g4 = *(const uint*)(xpB + ((uint)sv1.x + lane4));
            uint g5 = *(const uint*)(xpB + ((uint)sv1.y + lane4));
            uint g6 = *(const uint*)(xpB + ((uint)sv1.z + lane4));
            uint g7 = *(const uint*)(xpB + ((uint)sv1.w + lane4));
            den += ((e0 + e1) + (e2 + e3)) + ((e4 + e5) + (e6 + e7));
            acc0 = fmaf(e0, __uint_as_float(g0 << 16), acc0);
            acc1 = fmaf(e0, __uint_as_float(g0 & 0xffff0000u), acc1);
            acc0 = fmaf(e1, __uint_as_float(g1 << 16), acc0);
            acc1 = fmaf(e1, __uint_as_float(g1 & 0xffff0000u), acc1);
            acc0 = fmaf(e2, __uint_as_float(g2 << 16), acc0);
            acc1 = fmaf(e2, __uint_as_float(g2 & 0xffff0000u), acc1);
            acc0 = fmaf(e3, __uint_as_float(g3 << 16), acc0);
            acc1 = fmaf(e3, __uint_as_float(g3 & 0xffff0000u), acc1);
            acc0 = fmaf(e4, __uint_as_float(g4 << 16), acc0);
            acc1 = fmaf(e4, __uint_as_float(g4 & 0xffff0000u), acc1);
            acc0 = fmaf(e5, __uint_as_float(g5 << 16), acc0);
            acc1 = fmaf(e5, __uint_as_float(g5 & 0xffff0000u), acc1);
            acc0 = fmaf(e6, __uint_as_float(g6 << 16), acc0);
            acc1 = fmaf(e6, __uint_as_float(g6 & 0xffff0000u), acc1);
            acc0 = fmaf(e7, __uint_as_float(g7 << 16), acc0);
            acc1 = fmaf(e7, __uint_as_float(g7 & 0xffff0000u), acc1);
        }
    }
    float inv = 1.f / (den + 1e-12f);
    float2 b2 = ((const float2*)bias)[lane];
    float2 o;
    o.x = acc0 * inv + b2.x;
    o.y = acc1 * inv + b2.y;
    ((float2*)(out + (long)n * HD))[lane] = o;
}

extern "C" void kernel_launch(void* const* d_in, const int* in_sizes, int n_in,
                              void* d_out, int out_size, void* d_ws, size_t ws_size,
                              hipStream_t stream) {
    const float* x = (const float*)d_in[0];
    const int* ei = (const int*)d_in[1];
    const float* W = (const float*)d_in[2];
    const float* att_src = (const float*)d_in[3];
    const float* att_dst = (const float*)d_in[4];
    const float* bias = (const float*)d_in[5];
    float* out = (float*)d_out;
    char* ws = (char*)d_ws;

    // workspace layout (bytes), 16B-aligned
    ushort* xp       = (ushort*)(ws + 0);         // 25,600,000 (bf16 x_proj)
    float* asrc      = (float*)(ws + 25600000);   //  1,600,000
    float* adst      = (float*)(ws + 27200000);   //  1,600,000
    int* esrc        = (int*)(ws + 28800000);     //  6,400,000
    int* bpack       = (int*)(ws + 35200000);     //  6,400,000
    int* ghist       = (int*)(ws + 41600000);     //  1,223,048 (391*782 ints)
    int* part        = (int*)(ws + 42823648);     //        600
    int* row_start   = (int*)(ws + 42824256);     //    400,004
    ushort* wb       = (ushort*)(ws + 43224272);  //     32,768 (bf16 W)
    // total ~43.3 MB; no zero-init needed (every buffer fully written before read)

    k_chist<<<NBLK_E, 256, 0, stream>>>(ei, ghist, W, wb);
    k_s1<<<S1_BLKS, 256, 0, stream>>>(ghist, part);
    k_s23<<<S1_BLKS, 256, 0, stream>>>(ghist, part);
    k_cscatter<<<NBLK_E, 256, 0, stream>>>(ei, ghist, bpack);
    k_gemm<<<(N_NODES + 63) / 64, 256, 0, stream>>>(x, wb, xp, att_src, att_dst, asrc, adst);
    k_fine<<<NBIN, 256, 0, stream>>>(ghist, bpack, esrc, row_start);
    k_aggregate<<<(N_NODES + 3) / 4, 256, 0, stream>>>(row_start, esrc,
                                                       (const char*)asrc, (const float4*)adst,
                                                       (const char*)xp, bias, out);
}